// Round 14
// baseline (1436.847 us; speedup 1.0000x reference)
//
#include <hip/hip_runtime.h>
#include <cstdint>
#include <cstddef>
#include <cmath>

typedef unsigned short u16;
typedef unsigned int u32;
typedef __attribute__((ext_vector_type(8))) _Float16 f16x8;
typedef __attribute__((ext_vector_type(4))) float f32x4;

#define S_LEN 2048
#define DMODEL 2048
#define NHEAD 16
#define NKVH 4
#define HDIM 128
#define NQKV 3072
#define NF 2048
#define TA 4096
#define ATT_SCALE 0.08838834764831845f
#define LO_SCALE 1024.0f
#define LO_INV (1.0f/1024.0f)
#define DEFER_THR 8.0f

static __device__ __forceinline__ u16 f2h(float x){ _Float16 h=(_Float16)x; return __builtin_bit_cast(u16,h); }
static __device__ __forceinline__ float h2f(u16 u){ return (float)__builtin_bit_cast(_Float16,u); }
static __device__ __forceinline__ void split2(float x, u16& hi, u16& lo){
  hi = f2h(x);
  lo = f2h((x - h2f(hi)) * LO_SCALE);
}
// async global->LDS, 16B per lane; LDS dest = wave-uniform base + lane*16
static __device__ __forceinline__ void gload16(const u16* g, u16* l){
  __builtin_amdgcn_global_load_lds(
      (const __attribute__((address_space(1))) void*)g,
      (__attribute__((address_space(3))) void*)l, 16, 0, 0);
}
// XCD-aware block swizzle (requires nwg % 8 == 0)
static __device__ __forceinline__ void xcd_swz(int& bx, int& by){
  int gx = gridDim.x;
  int n = gx * gridDim.y;
  int bid = by*gx + bx;
  int cpx = n >> 3;
  int s = (bid & 7)*cpx + (bid >> 3);
  bx = s % gx; by = s / gx;
}

// ---------------- static attn work-item table (rank-sorted descending by size) ----------
__constant__ int c_itq[48] = {
  15,31,31,30,30,14,29,29,28,28,13,27,27,26,26,12,25,25,24,24,
  11,23,23,22,22,10,21,21,20,20, 9,19,19,18,18, 8,17,17,16,16,
   7, 6, 5, 4, 3, 2, 1, 0};
__constant__ int c_itk0[48] = {
   0, 0,32, 0,31, 0, 0,30, 0,29, 0, 0,28, 0,27, 0, 0,26, 0,25,
   0, 0,24, 0,23, 0, 0,22, 0,21, 0, 0,20, 0,19, 0, 0,18, 0,17,
   0, 0, 0, 0, 0, 0, 0, 0};
__constant__ int c_itk1[48] = {
  32,32,64,31,62,30,30,60,29,58,28,28,56,27,54,26,26,52,25,50,
  24,24,48,23,46,22,22,44,21,42,20,20,40,19,38,18,18,36,17,34,
  16,14,12,10, 8, 6, 4, 2};
__constant__ int c_itsl[48] = {
  -1,30,31,28,29,-1,26,27,24,25,-1,22,23,20,21,-1,18,19,16,17,
  -1,14,15,12,13,-1,10,11, 8, 9,-1, 6, 7, 4, 5,-1, 2, 3, 0, 1,
  -1,-1,-1,-1,-1,-1,-1,-1};

// ---------------- workspace layout (bytes) ----------------
#define WS_WOUTH ((size_t)0)
#define WS_WOUTL ((size_t)8388608)
#define WS_QKVTH ((size_t)16777216)
#define WS_QKVTL ((size_t)29360128)
#define WS_H1H   ((size_t)41943040)
#define WS_H1L   ((size_t)50331648)
#define WS_QKV   ((size_t)58720256)
#define WS_QH    ((size_t)16777216)
#define WS_QL    ((size_t)25165824)
#define WS_KH    ((size_t)33554432)
#define WS_KL    ((size_t)35651584)
#define WS_VTH   ((size_t)37748736)
#define WS_VTL   ((size_t)39845888)
#define WS_OH    ((size_t)41943040)
#define WS_OL    ((size_t)50331648)
#define WS_H2    ((size_t)58720256)
#define WS_X2    ((size_t)75497472)
#define WS_I1    ((size_t)0)
#define WS_Y     ((size_t)16777216)
#define WS_MOE   ((size_t)33554432)
#define WS_SM    ((size_t)83886080)
#define WS_WT0   ((size_t)84934656)
#define WS_WT1   ((size_t)152043520)
#define WS_BIG   ((size_t)219152384)
#define SM_INVT   0
#define SM_COUNTS 256
#define SM_FILL   320
#define SM_OFFS   384
#define SM_NT     448
#define SM_TE     512
#define SM_TRS    768
#define SM_E01    1024
#define SM_W01    (1024+16384)
#define SM_ATOK   (1024+2*16384)
#define SM_AW     (1024+3*16384)
#define SM_SLOT   (1024+4*16384)

// ---------------- init ----------------
__global__ void __launch_bounds__(64) init_k(int* counts, int* fill, float* invt){
  int t = threadIdx.x;
  if (t < 8) { counts[t] = 0; fill[t] = 0; }
  double di = (double)t * (1.0/64.0);
  float y = (float)pow(500000.0, di);
  invt[t] = 1.0f / y;
}

// ---------------- weight split+transpose, merged: z=0 -> Wqkv, z=1 -> Wout ----------------
__global__ void __launch_bounds__(256) wsplit2_k(
    const float* __restrict__ Wq, u16* __restrict__ Tqh, u16* __restrict__ Tql,
    const float* __restrict__ Wo, u16* __restrict__ Toh, u16* __restrict__ Tol){
  __shared__ float tile[32][33];
  int z = blockIdx.z;
  int N = z ? DMODEL : NQKV;
  if (z && blockIdx.x >= 64) return;
  const float* W = z ? Wo : Wq;
  u16* Th = z ? Toh : Tqh;
  u16* Tl = z ? Tol : Tql;
  int n0 = blockIdx.x*32, k0 = blockIdx.y*32;
  int tid = threadIdx.x;
  int rr = tid >> 3, cg = tid & 7;
  #pragma unroll
  for (int j=0;j<4;++j)
    tile[rr][cg*4+j] = W[(size_t)(k0+rr)*N + n0 + cg*4 + j];
  __syncthreads();
  int cc = tid >> 3, sg = tid & 7;
  #pragma unroll
  for (int j=0;j<4;++j){
    float x = tile[sg*4+j][cc];
    u16 hi, lo; split2(x, hi, lo);
    size_t idx = (size_t)(n0+cc)*2048 + k0 + sg*4 + j;
    Th[idx] = hi; Tl[idx] = lo;
  }
}

// ---------------- MoE weight convert+transpose: fp32 [e][k][n] -> f16 [e][n][k] ----------------
// Merged dual-weight variant: z=0..7 -> (Wa -> Ta), z=8..15 -> (Wb -> Tb)
__global__ void __launch_bounds__(256) wconvT2_k(const float* __restrict__ Wa,
    u16* __restrict__ Ta, const float* __restrict__ Wb, u16* __restrict__ Tb){
  __shared__ float tile[64][68];
  int z = blockIdx.z;
  const float* W = (z < 8) ? Wa : Wb;
  u16* T = (z < 8) ? Ta : Tb;
  int e = z & 7;
  int n0 = blockIdx.x*64, k0 = blockIdx.y*64;
  size_t ebase = (size_t)e * 2048 * 2048;
  int tid = threadIdx.x;
  int rr = tid >> 4, c4 = (tid & 15)*4;
  #pragma unroll
  for (int p=0;p<4;++p){
    float4 v = *(const float4*)(W + ebase + (size_t)(k0+p*16+rr)*2048 + n0 + c4);
    *(float4*)&tile[p*16+rr][c4] = v;
  }
  __syncthreads();
  int nn = tid >> 2, kc = (tid & 3)*16;
  u16 buf[16];
  #pragma unroll
  for (int j=0;j<16;++j) buf[j] = f2h(tile[kc+j][nn]);
  u16* dst = T + ebase + (size_t)(n0+nn)*2048 + k0 + kc;
  *(int4*)dst = *(int4*)&buf[0];
  *(int4*)(dst+8) = *(int4*)&buf[8];
}

// single-weight variant (w2, reuses wT0 after moe13)
__global__ void __launch_bounds__(256) wconvT_k(const float* __restrict__ W,
                                                u16* __restrict__ T){
  __shared__ float tile[64][68];
  int n0 = blockIdx.x*64, k0 = blockIdx.y*64;
  size_t ebase = (size_t)blockIdx.z * 2048 * 2048;
  int tid = threadIdx.x;
  int rr = tid >> 4, c4 = (tid & 15)*4;
  #pragma unroll
  for (int p=0;p<4;++p){
    float4 v = *(const float4*)(W + ebase + (size_t)(k0+p*16+rr)*2048 + n0 + c4);
    *(float4*)&tile[p*16+rr][c4] = v;
  }
  __syncthreads();
  int nn = tid >> 2, kc = (tid & 3)*16;
  u16 buf[16];
  #pragma unroll
  for (int j=0;j<16;++j) buf[j] = f2h(tile[kc+j][nn]);
  u16* dst = T + ebase + (size_t)(n0+nn)*2048 + k0 + kc;
  *(int4*)dst = *(int4*)&buf[0];
  *(int4*)(dst+8) = *(int4*)&buf[8];
}

__device__ __forceinline__ float blk_red_sum(float v, float* red, int tid){
  #pragma unroll
  for (int off=1; off<64; off<<=1) v += __shfl_xor(v, off);
  if ((tid&63)==0) red[tid>>6] = v;
  __syncthreads();
  float r = red[0]+red[1]+red[2]+red[3];
  __syncthreads();
  return r;
}

// ---------------- LN1 -> split planes ----------------
__global__ void __launch_bounds__(256) ln1_k(const float* __restrict__ X,
    const float* __restrict__ W, const float* __restrict__ Bv,
    u16* __restrict__ Hh, u16* __restrict__ Hl){
  __shared__ float red[4];
  int t = blockIdx.x, tid = threadIdx.x;
  const float* row = X + (size_t)t*DMODEL + tid*8;
  float4 a = *(const float4*)row;
  float4 b = *(const float4*)(row+4);
  float xs[8] = {a.x,a.y,a.z,a.w,b.x,b.y,b.z,b.w};
  float s = 0.f;
  #pragma unroll
  for (int j=0;j<8;++j) s += xs[j];
  float mu = blk_red_sum(s, red, tid) * (1.f/DMODEL);
  float sq = 0.f;
  #pragma unroll
  for (int j=0;j<8;++j){ float d = xs[j]-mu; sq += d*d; }
  float var = blk_red_sum(sq, red, tid) * (1.f/DMODEL);
  float rs = 1.0f/sqrtf(var + 1e-5f);
  float4 w0 = *(const float4*)(W + tid*8);
  float4 w1 = *(const float4*)(W + tid*8 + 4);
  float4 b0 = *(const float4*)(Bv + tid*8);
  float4 b1 = *(const float4*)(Bv + tid*8 + 4);
  float ws_[8] = {w0.x,w0.y,w0.z,w0.w,w1.x,w1.y,w1.z,w1.w};
  float bs_[8] = {b0.x,b0.y,b0.z,b0.w,b1.x,b1.y,b1.z,b1.w};
  u32 ph[4], pl[4];
  #pragma unroll
  for (int j=0;j<4;++j){
    u16 h0,l0,h1,l1;
    split2((xs[2*j]-mu)*rs*ws_[2*j]+bs_[2*j], h0, l0);
    split2((xs[2*j+1]-mu)*rs*ws_[2*j+1]+bs_[2*j+1], h1, l1);
    ph[j] = (u32)h0 | ((u32)h1<<16);
    pl[j] = (u32)l0 | ((u32)l1<<16);
  }
  int4 vh; vh.x=(int)ph[0]; vh.y=(int)ph[1]; vh.z=(int)ph[2]; vh.w=(int)ph[3];
  int4 vl; vl.x=(int)pl[0]; vl.y=(int)pl[1]; vl.z=(int)pl[2]; vl.w=(int)pl[3];
  *(int4*)(Hh + (size_t)t*DMODEL + tid*8) = vh;
  *(int4*)(Hl + (size_t)t*DMODEL + tid*8) = vl;
}

// ---------------- split-precision GEMM, 128(M)x64(N) tile, BK=64 ----------------
template<int MODE>
__global__ void __launch_bounds__(256) gemm32_k(
    const u16* __restrict__ Ahp, const u16* __restrict__ Alp,
    const u16* __restrict__ Bhp, const u16* __restrict__ Blp,
    float* __restrict__ C, const float* __restrict__ res)
{
  constexpr int K = 2048;
  __shared__ u16 Ash[128*64], Asl[128*64], Bsh[64*64], Bsl[64*64];
  int bx = blockIdx.x, by = blockIdx.y;
  xcd_swz(bx, by);
  int m0 = by*128, n0 = bx*64;
  int tid = threadIdx.x, w = tid>>6, lane = tid&63;
  int l15 = lane&15, l4 = lane>>4, wr = w>>1, wc = w&1;
  int srow8 = lane >> 3;
  int sslot = ((lane&7) ^ srow8) * 8;

  f32x4 accH[4][2] = {}, accC[4][2] = {};

  for (int k0 = 0; k0 < K; k0 += 64){
    __syncthreads();
    #pragma unroll
    for (int c=0;c<4;++c){
      int row = w*32 + c*8 + srow8;
      size_t ga = (size_t)(m0+row)*K + k0 + sslot;
      gload16(Ahp+ga, &Ash[(w*32+c*8)*64]);
      gload16(Alp+ga, &Asl[(w*32+c*8)*64]);
    }
    #pragma unroll
    for (int c=0;c<2;++c){
      int rowb = w*16 + c*8 + srow8;
      size_t gb = (size_t)(n0+rowb)*K + k0 + sslot;
      gload16(Bhp+gb, &Bsh[(w*16+c*8)*64]);
      gload16(Blp+gb, &Bsl[(w*16+c*8)*64]);
    }
    __syncthreads();
    #pragma unroll
    for (int kk=0; kk<2; ++kk){
      int xslot = ((kk*4 + l4) ^ (l15 & 7)) * 8;
      f16x8 ah[4], al[4];
      #pragma unroll
      for (int mi=0; mi<4; ++mi){
        int row = wr*64 + mi*16 + l15;
        ah[mi] = *(const f16x8*)&Ash[row*64 + xslot];
        al[mi] = *(const f16x8*)&Asl[row*64 + xslot];
      }
      #pragma unroll
      for (int ni=0; ni<2; ++ni){
        int row = wc*32 + ni*16 + l15;
        f16x8 bh = *(const f16x8*)&Bsh[row*64 + xslot];
        f16x8 bl = *(const f16x8*)&Bsl[row*64 + xslot];
        #pragma unroll
        for (int mi=0; mi<4; ++mi){
          accH[mi][ni] = __builtin_amdgcn_mfma_f32_16x16x32_f16(ah[mi], bh, accH[mi][ni], 0,0,0);
          accC[mi][ni] = __builtin_amdgcn_mfma_f32_16x16x32_f16(ah[mi], bl, accC[mi][ni], 0,0,0);
          accC[mi][ni] = __builtin_amdgcn_mfma_f32_16x16x32_f16(al[mi], bh, accC[mi][ni], 0,0,0);
        }
      }
    }
  }

  #pragma unroll
  for (int mi=0; mi<4; ++mi){
    #pragma unroll
    for (int ni=0; ni<2; ++ni){
      #pragma unroll
      for (int r=0; r<4; ++r){
        int rl = wr*64 + mi*16 + l4*4 + r;
        int cl = wc*32 + ni*16 + l15;
        float v = accH[mi][ni][r] + accC[mi][ni][r]*LO_INV;
        if constexpr (MODE == 0){
          v = fminf(fmaxf(v, -8.f), 8.f);
          C[(size_t)(m0 + rl)*NQKV + n0 + cl] = v;
        } else {
          size_t idx = (size_t)(m0 + rl)*DMODEL + n0 + cl;
          C[idx] = v + res[idx];
        }
      }
    }
  }
}

// ---------------- merged RoPE + V-transpose (both read qkv only) ----------------
__global__ void __launch_bounds__(256) ropevt_k(const float* __restrict__ qkv,
    const int* __restrict__ pos_ids, const float* __restrict__ invt,
    u16* __restrict__ Qh, u16* __restrict__ Ql, u16* __restrict__ Kh, u16* __restrict__ Kl,
    u16* __restrict__ Vth, u16* __restrict__ Vtl){
  __shared__ float tile[32][33];
  int bid = blockIdx.x;
  int tid = threadIdx.x;
  if (bid < S_LEN){
    int s = bid;
    float pos = (float)pos_ids[s];
    const float* row = qkv + (size_t)s*NQKV;
    for (int p = tid; p < 1280; p += 256){
      int i = p & 63;
      float ang = pos * invt[i];
      float sn, cs;
      sincosf(ang, &sn, &cs);
      u16 h1_,l1_,h2_,l2_;
      if (p < 1024){
        int h = p >> 6;
        float x1 = row[h*HDIM + i];
        float x2 = row[h*HDIM + 64 + i];
        size_t base = ((size_t)h*S_LEN + s)*HDIM;
        split2(x1*cs - x2*sn, h1_, l1_);
        split2(x2*cs + x1*sn, h2_, l2_);
        Qh[base + i] = h1_; Ql[base + i] = l1_;
        Qh[base + 64 + i] = h2_; Ql[base + 64 + i] = l2_;
      } else {
        int kh = (p-1024) >> 6;
        float x1 = row[2048 + kh*HDIM + i];
        float x2 = row[2048 + kh*HDIM + 64 + i];
        size_t base = ((size_t)kh*S_LEN + s)*HDIM;
        split2(x1*cs - x2*sn, h1_, l1_);
        split2(x2*cs + x1*sn, h2_, l2_);
        Kh[base + i] = h1_; Kl[base + i] = l1_;
        Kh[base + 64 + i] = h2_; Kl[base + 64 + i] = l2_;
      }
    }
  } else {
    int t = bid - S_LEN;            // 0..1023
    int s0 = (t & 63)*32, c0 = (t >> 6)*32;
    int rr = tid >> 3, cg = tid & 7;
    #pragma unroll
    for (int j=0;j<4;++j)
      tile[rr][cg*4+j] = qkv[(size_t)(s0+rr)*NQKV + 2560 + c0 + cg*4 + j];
    __syncthreads();
    int cc = tid >> 3, sg = tid & 7;
    #pragma unroll
    for (int j=0;j<4;++j){
      float x = tile[sg*4+j][cc];
      u16 hi, lo; split2(x, hi, lo);
      size_t idx = (size_t)(c0+cc)*S_LEN + s0 + sg*4 + j;
      Vth[idx] = hi; Vtl[idx] = lo;
    }
  }
}

// ---------------- flash attention (split precision, deferred max, KV-split items) ----------------
__global__ void __launch_bounds__(256, 3) attn_k(
    const u16* __restrict__ Qhp, const u16* __restrict__ Qlp,
    const u16* __restrict__ Khp, const u16* __restrict__ Klp,
    const u16* __restrict__ Vthp, const u16* __restrict__ Vtlp,
    u16* __restrict__ Oh, u16* __restrict__ Ol,
    float* __restrict__ Opart, float* __restrict__ Mlp){
  __shared__ u16 Ksh[32*128], Ksl[32*128];
  __shared__ u16 Vsh[128*32], Vsl[128*32];
  __shared__ u16 Psh[4*16*40], Psl[4*16*40];
  int tid = threadIdx.x;
  int w = tid>>6, lane = tid&63, l15 = lane&15, l4 = lane>>4;
  int rank = blockIdx.x >> 4, h = blockIdx.x & 15, kvh = h >> 2;
  int qb = c_itq[rank], kb0 = c_itk0[rank], kb1 = c_itk1[rank], sl = c_itsl[rank];
  int q0 = qb*64 + w*16;
  f16x8 qfh[4], qfl[4];
  #pragma unroll
  for (int ds=0; ds<4; ++ds){
    size_t off = ((size_t)h*S_LEN + q0 + l15)*HDIM + ds*32 + l4*8;
    qfh[ds] = *(const f16x8*)(Qhp + off);
    qfl[ds] = *(const f16x8*)(Qlp + off);
  }
  f32x4 accH[8] = {}, accC[8] = {};
  float m_r[4], l_r[4];
  #pragma unroll
  for (int r=0;r<4;++r){ m_r[r] = -1e30f; l_r[r] = 0.f; }
  for (int kb = kb0; kb < kb1; ++kb){
    int kbase = kb*32;
    __syncthreads();
    #pragma unroll
    for (int c=0;c<2;++c){
      int krow = w*8 + c*4 + l4;
      int ks = l15;
      int kcol = ((ks&8) | ((ks&7) ^ (krow&7)))*8;
      size_t koff = ((size_t)kvh*S_LEN + kbase + krow)*HDIM + kcol;
      gload16(Khp + koff, &Ksh[(w*8+c*4)*128]);
      gload16(Klp + koff, &Ksl[(w*8+c*4)*128]);
      int vrow = w*32 + c*16 + (lane>>2);
      int vcol = ((lane&3) ^ ((lane>>3)&3))*8;
      size_t voff = ((size_t)kvh*HDIM + vrow)*S_LEN + kbase + vcol;
      gload16(Vthp + voff, &Vsh[(w*32+c*16)*32]);
      gload16(Vtlp + voff, &Vsl[(w*32+c*16)*32]);
    }
    __syncthreads();
    // QK^T
    f32x4 sH0 = {}, sH1 = {}, sC0 = {}, sC1 = {};
    __builtin_amdgcn_s_setprio(1);
    #pragma unroll
    for (int ds=0; ds<4; ++ds){
      int ksl = ds*4 + l4;
      int klds = ((ksl&8) | ((ksl&7) ^ (l15&7)))*8;
      f16x8 kh0 = *(const f16x8*)&Ksh[l15*128 + klds];
      f16x8 kl0 = *(const f16x8*)&Ksl[l15*128 + klds];
      f16x8 kh1 = *(const f16x8*)&Ksh[(16+l15)*128 + klds];
      f16x8 kl1 = *(const f16x8*)&Ksl[(16+l15)*128 + klds];
      sH0 = __builtin_amdgcn_mfma_f32_16x16x32_f16(qfh[ds], kh0, sH0, 0,0,0);
      sC0 = __builtin_amdgcn_mfma_f32_16x16x32_f16(qfh[ds], kl0, sC0, 0,0,0);
      sC0 = __builtin_amdgcn_mfma_f32_16x16x32_f16(qfl[ds], kh0, sC0, 0,0,0);
      sH1 = __builtin_amdgcn_mfma_f32_16x16x32_f16(qfh[ds], kh1, sH1, 0,0,0);
      sC1 = __builtin_amdgcn_mfma_f32_16x16x32_f16(qfh[ds], kl1, sC1, 0,0,0);
      sC1 = __builtin_amdgcn_mfma_f32_16x16x32_f16(qfl[ds], kh1, sC1, 0,0,0);
    }
    __builtin_amdgcn_s_setprio(0);
    // softmax with deferred max (THR=8)
    float v0[4], v1[4];
    bool need = false;
    #pragma unroll
    for (int r=0;r<4;++r){
      int qg = q0 + l4*4 + r;
      v0[r] = (sH0[r] + sC0[r]*LO_INV)*ATT_SCALE; if (kbase + l15 > qg) v0[r] = -1e9f;
      v1[r] = (sH1[r] + sC1[r]*LO_INV)*ATT_SCALE; if (kbase + 16 + l15 > qg) v1[r] = -1e9f;
      float pm = fmaxf(v0[r], v1[r]);
      need = need || (pm > m_r[r] + DEFER_THR);
    }
    if (__any(need)){
      float fac[4];
      #pragma unroll
      for (int r=0;r<4;++r){
        float mx = fmaxf(v0[r], v1[r]);
        mx = fmaxf(mx, __shfl_xor(mx,1));
        mx = fmaxf(mx, __shfl_xor(mx,2));
        mx = fmaxf(mx, __shfl_xor(mx,4));
        mx = fmaxf(mx, __shfl_xor(mx,8));
        float mnew = fmaxf(m_r[r], mx);
        fac[r] = __expf(m_r[r] - mnew);
        l_r[r] *= fac[r];
        m_r[r] = mnew;
      }
      #pragma unroll
      for (int nt=0; nt<8; ++nt){
        #pragma unroll
        for (int r=0;r<4;++r){ accH[nt][r] *= fac[r]; accC[nt][r] *= fac[r]; }
      }
    }
    #pragma unroll
    for (int r=0;r<4;++r){
      float p0 = __expf(v0[r] - m_r[r]);
      float p1 = __expf(v1[r] - m_r[r]);
      l_r[r] += p0 + p1;
      u16 hi, lo;
      split2(p0, hi, lo);
      Psh[w*640 + (l4*4+r)*40 + l15] = hi;
      Psl[w*640 + (l4*4+r)*40 + l15] = lo;
      split2(p1, hi, lo);
      Psh[w*640 + (l4*4+r)*40 + 16 + l15] = hi;
      Psl[w*640 + (l4*4+r)*40 + 16 + l15] = lo;
    }
    // P is wave-private LDS: program order + lgkmcnt suffice
    f16x8 pfh = *(const f16x8*)&Psh[w*640 + l15*40 + l4*8];
    f16x8 pfl = *(const f16x8*)&Psl[w*640 + l15*40 + l4*8];
    __builtin_amdgcn_s_setprio(1);
    #pragma unroll
    for (int nt=0; nt<8; ++nt){
      int vsl = (l4 ^ ((l15>>1)&3))*8;
      f16x8 vh = *(const f16x8*)&Vsh[(nt*16 + l15)*32 + vsl];
      f16x8 vl = *(const f16x8*)&Vsl[(nt*16 + l15)*32 + vsl];
      accH[nt] = __builtin_amdgcn_mfma_f32_16x16x32_f16(pfh, vh, accH[nt], 0,0,0);
      f32x4 aC = __builtin_amdgcn_mfma_f32_16x16x32_f16(pfh, vl, accC[nt], 0,0,0);
      accC[nt] = __builtin_amdgcn_mfma_f32_16x16x32_f16(pfl, vh, aC, 0,0,0);
    }
    __builtin_amdgcn_s_setprio(0);
  }
  // final l reduction over the 16 k-lanes
  #pragma unroll
  for (int r=0;r<4;++r){
    float l = l_r[r];
    l += __shfl_xor(l,1); l += __shfl_xor(l,2);
    l += __shfl_xor(l,4); l += __shfl_xor(l,8);
    l_r[r] = l;
  }
  if (sl < 0){
    #pragma unroll
    for (int nt=0; nt<8; ++nt){
      #pragma unroll
      for (int r=0;r<4;++r){
        int row = q0 + l4*4 + r;
        int col = h*HDIM + nt*16 + l15;
        float val = (accH[nt][r] + accC[nt][r]*LO_INV) / l_r[r];
        u16 hi, lo; split2(val, hi, lo);
        Oh[(size_t)row*DMODEL + col] = hi;
        Ol[(size_t)row*DMODEL + col] = lo;
      }
    }
  } else {
    int slot = sl*16 + h;
    float* Op = Opart + (size_t)slot*8192;
    #pragma unroll
    for (int nt=0; nt<8; ++nt){
      #pragma unroll
      for (int r=0;r<4;++r){
        int row = w*16 + l4*4 + r;
        Op[row*128 + nt*16 + l15] = accH[nt][r] + accC[nt][r]*LO_INV;
      }
    }
    if (l15 == 0){
      #pragma unroll
      for (int r=0;r<4;++r){
        int row = w*16 + l4*4 + r;
        Mlp[slot*128 + row*2]     = m_r[r];
        Mlp[slot*128 + row*2 + 1] = l_r[r];
      }
    }
  }
}

// ---------------- merge two KV-half partials -> Oh/Ol ----------------
__global__ void __launch_bounds__(256) merge_k(const float* __restrict__ Op,
    const float* __restrict__ Ml, u16* __restrict__ Oh, u16* __restrict__ Ol){
  int qb = 16 + blockIdx.x, h = blockIdx.y;
  int slot1 = ((qb-16)*2)*16 + h;
  int slot2 = slot1 + 16;
  int tid = threadIdx.x;
  int rr = tid >> 2, cg = (tid & 3) * 32;
  float m1 = Ml[slot1*128 + rr*2], l1 = Ml[slot1*128 + rr*2 + 1];
  float m2 = Ml[slot2*128 + rr*2], l2 = Ml[slot2*128 + rr*2 + 1];
  float M = fmaxf(m1, m2);
  float a1 = __expf(m1 - M), a2 = __expf(m2 - M);
  float inv = 1.f / (l1*a1 + l2*a2);
  const float* p1 = Op + (size_t)slot1*8192 + rr*128 + cg;
  const float* p2 = Op + (size_t)slot2*8192 + rr*128 + cg;
  size_t ob = (size_t)(qb*64 + rr)*DMODEL + h*HDIM + cg;
  #pragma unroll
  for (int j = 0; j < 32; j += 4){
    float4 o1 = *(const float4*)(p1 + j);
    float4 o2 = *(const float4*)(p2 + j);
    float vals[4] = {(o1.x*a1+o2.x*a2)*inv, (o1.y*a1+o2.y*a2)*inv,
                     (o1.z*a1+o2.z*a2)*inv, (o1.w*a1+o2.w*a2)*inv};
    u16 hs[4], ls[4];
    #pragma unroll
    for (int c=0;c<4;++c) split2(vals[c], hs[c], ls[c]);
    *(uint2*)(Oh + ob + j) = *(uint2*)&hs[0];
    *(uint2*)(Ol + ob + j) = *(uint2*)&ls[0];
  }
}

// ---------------- LN2 + router ----------------
__global__ void __launch_bounds__(256) ln2_router_k(const float* __restrict__ H2,
    const float* __restrict__ W, const float* __restrict__ Bv,
    const float* __restrict__ Wr, u16* __restrict__ X2,
    int* __restrict__ e01, float* __restrict__ w01, int* __restrict__ counts){
  __shared__ float red[4];
  __shared__ float lred[4][8];
  int t = blockIdx.x, tid = threadIdx.x;
  const float* row = H2 + (size_t)t*DMODEL + tid*8;
  float4 a = *(const float4*)row;
  float4 b = *(const float4*)(row+4);
  float xs[8] = {a.x,a.y,a.z,a.w,b.x,b.y,b.z,b.w};
  float s = 0.f;
  #pragma unroll
  for (int j=0;j<8;++j) s += xs[j];
  float mu = blk_red_sum(s, red, tid) * (1.f/DMODEL);
  float sq = 0.f;
  #pragma unroll
  for (int j=0;j<8;++j){ float d = xs[j]-mu; sq += d*d; }
  float var = blk_red_sum(sq, red, tid) * (1.f/DMODEL);
  float rs = 1.0f/sqrtf(var + 1e-5f);
  float4 w0 = *(const float4*)(W + tid*8);
  float4 w1 = *(const float4*)(W + tid*8 + 4);
  float4 b0 = *(const float4*)(Bv + tid*8);
  float4 b1 = *(const float4*)(Bv + tid*8 + 4);
  float ws_[8] = {w0.x,w0.y,w0.z,w0.w,w1.x,w1.y,w1.z,w1.w};
  float bs_[8] = {b0.x,b0.y,b0.z,b0.w,b1.x,b1.y,b1.z,b1.w};
  float xn[8];
  #pragma unroll
  for (int j=0;j<8;++j) xn[j] = (xs[j]-mu)*rs*ws_[j]+bs_[j];
  u32 pk[4];
  #pragma unroll
  for (int j=0;j<4;++j) pk[j] = (u32)f2h(xn[2*j]) | ((u32)f2h(xn[2*j+1])<<16);
  int4 v; v.x=(int)pk[0]; v.y=(int)pk[1]; v.z=(int)pk[2]; v.w=(int)pk[3];
  *(int4*)(X2 + (size_t)t*DMODEL + tid*8) = v;
  float lg[8] = {0,0,0,0,0,0,0,0};
  #pragma unroll
  for (int j=0;j<8;++j){
    const float* wrp = Wr + (size_t)(tid*8 + j)*8;
    float4 wa = *(const float4*)wrp;
    float4 wb = *(const float4*)(wrp+4);
    lg[0]+=xn[j]*wa.x; lg[1]+=xn[j]*wa.y; lg[2]+=xn[j]*wa.z; lg[3]+=xn[j]*wa.w;
    lg[4]+=xn[j]*wb.x; lg[5]+=xn[j]*wb.y; lg[6]+=xn[j]*wb.z; lg[7]+=xn[j]*wb.w;
  }
  #pragma unroll
  for (int e=0;e<8;++e){
    #pragma unroll
    for (int off=1; off<64; off<<=1) lg[e] += __shfl_xor(lg[e], off);
  }
  if ((tid&63)==0){
    #pragma unroll
    for (int e=0;e<8;++e) lred[tid>>6][e] = lg[e];
  }
  __syncthreads();
  if (tid==0){
    float L[8];
    #pragma unroll
    for (int e=0;e<8;++e) L[e] = lred[0][e]+lred[1][e]+lred[2][e]+lred[3][e];
    int e0 = 0;
    #pragma unroll
    for (int e=1;e<8;++e) if (L[e] > L[e0]) e0 = e;
    int e1 = (e0==0)?1:0;
    #pragma unroll
    for (int e=0;e<8;++e) if (e!=e0 && L[e] > L[e1]) e1 = e;
    float ax = expf(L[e1]-L[e0]);
    float z = 1.f/(1.f+ax);
    e01[2*t] = e0; e01[2*t+1] = e1;
    w01[2*t] = z;  w01[2*t+1] = ax*z;
    atomicAdd(&counts[e0],1); atomicAdd(&counts[e1],1);
  }
}

__global__ void __launch_bounds__(64) htiles_k(const int* counts, int* offs, int* ntl,
                                               int* te, int* trs){
  if (threadIdx.x==0){
    int off=0;
    for (int e=0;e<8;++e){ offs[e]=off; off+=counts[e]; }
    offs[8]=off;
    int nt=0;
    for (int e=0;e<8;++e)
      for (int j=0; j*128 < counts[e]; ++j){ te[nt]=e; trs[nt]=j*128; nt++; }
    ntl[0]=nt;
  }
}

__global__ void __launch_bounds__(256) scatter_k(const int* __restrict__ e01,
    const float* __restrict__ w01, const int* __restrict__ offs, int* __restrict__ fill,
    int* __restrict__ atok, float* __restrict__ aw, int* __restrict__ slots){
  int t = blockIdx.x*256 + threadIdx.x;
  if (t >= S_LEN) return;
  int e0 = e01[2*t], e1 = e01[2*t+1];
  int p0 = offs[e0] + atomicAdd(&fill[e0],1);
  atok[p0] = t; aw[p0] = w01[2*t]; slots[2*t] = p0;
  int p1 = offs[e1] + atomicAdd(&fill[e1],1);
  atok[p1] = t; aw[p1] = w01[2*t+1]; slots[2*t+1] = p1;
}

// ---------------- fused grouped GEMM: Y = silu(x@w1)*(x@v1), 128x128 tile, BK=64, 8 waves ----
// Arithmetic-intensity retile: B tiles amortized over 128 A-rows; per-wave acc unchanged.
__global__ void __launch_bounds__(512, 6) gemm_moe13_k(
    const u16* __restrict__ A, const u16* __restrict__ B1T, const u16* __restrict__ B2T,
    u16* __restrict__ Y,
    const int* __restrict__ atok, const int* __restrict__ counts,
    const int* __restrict__ offs, const int* __restrict__ ntl,
    const int* __restrict__ te, const int* __restrict__ trs)
{
  constexpr int K = 2048;
  __shared__ u16 As[128*64], B1s[128*64], B2s[128*64];
  int bx = blockIdx.x, by = blockIdx.y;
  xcd_swz(bx, by);
  if (by >= ntl[0]) return;
  int e = te[by];
  int rsu = trs[by];
  int base = offs[e] + rsu;
  int valid = min(128, counts[e] - rsu);
  const u16* B1p = B1T + (size_t)e * 2048 * 2048;
  const u16* B2p = B2T + (size_t)e * 2048 * 2048;
  int tid = threadIdx.x, w = tid>>6, lane = tid&63;
  int l15 = lane & 15, l4 = lane >> 4;
  int wr = w >> 2, wc = w & 3;         // 2 x 4 wave grid; wave tile 64 rows x 32 cols
  int srow8 = lane >> 3;
  int sslot = ((lane&7) ^ srow8) * 8;
  int n0 = bx*128;
  int tokc[2];
  #pragma unroll
  for (int c=0;c<2;++c){
    int rr = w*16 + c*8 + srow8;
    tokc[c] = atok[min(base + rr, TA-1)] & (S_LEN-1);
  }

  f32x4 acc1[4][2] = {}, acc2[4][2] = {};

  for (int k0 = 0; k0 < K; k0 += 64){
    __syncthreads();
    #pragma unroll
    for (int c=0;c<2;++c){
      int rr = w*16 + c*8;
      gload16(A + (size_t)tokc[c]*K + k0 + sslot, &As[(rr)*64]);
      size_t gb = (size_t)(n0 + rr + srow8)*K + k0 + sslot;
      gload16(B1p + gb, &B1s[(rr)*64]);
      gload16(B2p + gb, &B2s[(rr)*64]);
    }
    __syncthreads();
    #pragma unroll
    for (int kk=0; kk<2; ++kk){
      int xslot = ((kk*4 + l4) ^ (l15 & 7)) * 8;
      f16x8 af[4];
      #pragma unroll
      for (int mi=0; mi<4; ++mi)
        af[mi] = *(const f16x8*)&As[(wr*64 + mi*16 + l15)*64 + xslot];
      #pragma unroll
      for (int ni=0; ni<2; ++ni){
        int row = wc*32 + ni*16 + l15;
        f16x8 b1 = *(const f16x8*)&B1s[row*64 + xslot];
        f16x8 b2 = *(const f16x8*)&B2s[row*64 + xslot];
        #pragma unroll
        for (int mi=0; mi<4; ++mi){
          acc1[mi][ni] = __builtin_amdgcn_mfma_f32_16x16x32_f16(af[mi], b1, acc1[mi][ni], 0,0,0);
          acc2[mi][ni] = __builtin_amdgcn_mfma_f32_16x16x32_f16(af[mi], b2, acc2[mi][ni], 0,0,0);
        }
      }
    }
  }

  #pragma unroll
  for (int mi=0; mi<4; ++mi){
    #pragma unroll
    for (int ni=0; ni<2; ++ni){
      #pragma unroll
      for (int r=0; r<4; ++r){
        int rl = wr*64 + mi*16 + l4*4 + r;
        if (rl >= valid) continue;
        int col = n0 + wc*32 + ni*16 + l15;
        float a = acc1[mi][ni][r];
        float sl = a / (1.f + __expf(-a));
        Y[(size_t)(base + rl)*NF + col] = f2h(sl * acc2[mi][ni][r]);
      }
    }
  }
}

// ---------------- grouped GEMM for MoE, 128x64 tile, BK=64 ----------------
template<int MODE>
__global__ void __launch_bounds__(256) gemm_moe_k(
    const u16* __restrict__ A, const u16* __restrict__ BT, void* __restrict__ C,
    const u16* __restrict__ i1g, const float* __restrict__ aw,
    const int* __restrict__ atok, const int* __restrict__ counts,
    const int* __restrict__ offs, const int* __restrict__ ntl,
    const int* __restrict__ te, const int* __restrict__ trs)
{
  constexpr int K = 2048;
  __shared__ u16 As[128*64], Bs[64*64];
  int bx = blockIdx.x, by = blockIdx.y;
  xcd_swz(bx, by);
  if (by >= ntl[0]) return;
  int e = te[by];
  int rsu = trs[by];
  int base = offs[e] + rsu;
  int valid = min(128, counts[e] - rsu);
  const u16* Bp = BT + (size_t)e * 2048 * 2048;
  int tid = threadIdx.x, w = tid>>6, lane = tid&63;
  int l15 = lane & 15, l4 = lane >> 4;
  int wr = w >> 1, wc = w & 1;
  int srow8 = lane >> 3;
  int sslot = ((lane&7) ^ srow8) * 8;
  int n0 = bx*64;
  int tokc[4];
  #pragma unroll
  for (int c=0;c<4;++c){
    int rr = w*32 + c*8 + srow8;
    if constexpr (MODE == 2 || MODE == 3)
      tokc[c] = atok[min(base + rr, TA-1)] & (S_LEN-1);
    else
      tokc[c] = min(base + rr, TA-1);
  }

  f32x4 acc[4][2] = {};

  for (int k0 = 0; k0 < K; k0 += 64){
    __syncthreads();
    #pragma unroll
    for (int c=0;c<4;++c)
      gload16(A + (size_t)tokc[c]*K + k0 + sslot, &As[(w*32+c*8)*64]);
    #pragma unroll
    for (int c=0;c<2;++c){
      int rowb = w*16 + c*8 + srow8;
      gload16(Bp + (size_t)(n0+rowb)*K + k0 + sslot, &Bs[(w*16+c*8)*64]);
    }
    __syncthreads();
    #pragma unroll
    for (int kk=0; kk<2; ++kk){
      int xslot = ((kk*4 + l4) ^ (l15 & 7)) * 8;
      f16x8 af[4];
      #pragma unroll
      for (int mi=0; mi<4; ++mi)
        af[mi] = *(const f16x8*)&As[(wr*64 + mi*16 + l15)*64 + xslot];
      #pragma unroll
      for (int ni=0; ni<2; ++ni){
        f16x8 bfv = *(const f16x8*)&Bs[(wc*32 + ni*16 + l15)*64 + xslot];
        #pragma unroll
        for (int mi=0; mi<4; ++mi)
          acc[mi][ni] = __builtin_amdgcn_mfma_f32_16x16x32_f16(af[mi], bfv, acc[mi][ni], 0,0,0);
      }
    }
  }

  #pragma unroll
  for (int mi=0; mi<4; ++mi){
    #pragma unroll
    for (int ni=0; ni<2; ++ni){
      f32x4 v = acc[mi][ni];
      #pragma unroll
      for (int r=0; r<4; ++r){
        int rl = wr*64 + mi*16 + l4*4 + r;
        if (rl >= valid) continue;
        int col = n0 + wc*32 + ni*16 + l15;
        if constexpr (MODE == 2){
          ((u16*)C)[(size_t)(base + rl)*NF + col] = f2h(v[r]);
        } else if constexpr (MODE == 3){
          size_t idx = (size_t)(base + rl)*NF + col;
          float a = h2f(i1g[idx]);
          float sl = a / (1.f + __expf(-a));
          ((u16*)C)[idx] = f2h(sl * v[r]);
        } else {
          float wgt = aw[base + rl];
          ((u16*)C)[(size_t)(base + rl)*DMODEL + col] = f2h(v[r] * wgt);
        }
      }
    }
  }
}

__global__ void __launch_bounds__(256) combine_k(const float* __restrict__ H2,
    const u16* __restrict__ MOE, const int* __restrict__ slots, float* __restrict__ out){
  int t = blockIdx.x, tid = threadIdx.x;
  int s0 = slots[2*t], s1 = slots[2*t+1];
  const float* h2p = H2 + (size_t)t*DMODEL + tid*8;
  int4 b0 = *(const int4*)(MOE + (size_t)s0*DMODEL + tid*8);
  int4 b1 = *(const int4*)(MOE + (size_t)s1*DMODEL + tid*8);
  const u16* bp0 = (const u16*)&b0;
  const u16* bp1 = (const u16*)&b1;
  float* op = out + (size_t)t*DMODEL + tid*8;
  #pragma unroll
  for (int j=0;j<8;++j)
    op[j] = h2p[j] + h2f(bp0[j]) + h2f(bp1[j]);
}

// ---------------- launch ----------------
extern "C" void kernel_launch(void* const* d_in, const int* in_sizes, int n_in,
                              void* d_out, int out_size, void* d_ws, size_t ws_size,
                              hipStream_t stream){
  const float* hidden = (const float*)d_in[0];
  const int*   pos    = (const int*)d_in[1];
  const float* ln1w   = (const float*)d_in[2];
  const float* ln1b   = (const float*)d_in[3];
  const float* ln2w   = (const float*)d_in[4];
  const float* ln2b   = (const float*)d_in[5];
  const float* Wqkv   = (const float*)d_in[6];
  const float* Wout   = (const float*)d_in[7];
  const float* Wr     = (const float*)d_in[8];
  const float* w1     = (const float*)d_in[9];
  const float* v1     = (const float*)d_in[10];
  const float* w2     = (const float*)d_in[11];
  float* out = (float*)d_out;
  char* ws = (char*)d_ws;

  u16* woutTh = (u16*)(ws + WS_WOUTH);
  u16* woutTl = (u16*)(ws + WS_WOUTL);
  u16* qkvTh  = (u16*)(ws + WS_QKVTH);
  u16* qkvTl  = (u16*)(ws + WS_QKVTL);
  u16* h1h = (u16*)(ws + WS_H1H);
  u16* h1l = (u16*)(ws + WS_H1L);
  float* qkv = (float*)(ws + WS_QKV);
  u16* Qh = (u16*)(ws + WS_QH);
  u16* Ql = (u16*)(ws + WS_QL);
  u16* Kh = (u16*)(ws + WS_KH);
  u16* Kl = (u16*)(ws + WS_KL);
  u16* Vth = (u16*)(ws + WS_VTH);
  u16* Vtl = (u16*)(ws + WS_VTL);
  u16* Oh = (u16*)(ws + WS_OH);
  u16* Ol = (u16*)(ws + WS_OL);
  float* h2 = (float*)(ws + WS_H2);
  u16* x2 = (u16*)(ws + WS_X2);
  u16* i1 = (u16*)(ws + WS_I1);
  u16* Yb = (u16*)(ws + WS_Y);
  u16* moe = (u16*)(ws + WS_MOE);
  u16* wT0 = (u16*)(ws + WS_WT0);
  u16* wT1 = (u16*)(ws + WS_WT1);
  float* Opart = (float*)(ws + WS_QKV);
  float* Mlp   = (float*)(ws + WS_X2);
  char* sm = ws + WS_SM;
  float* invt = (float*)(sm + SM_INVT);
  int* counts = (int*)(sm + SM_COUNTS);
  int* fill   = (int*)(sm + SM_FILL);
  int* offs   = (int*)(sm + SM_OFFS);
  int* ntl    = (int*)(sm + SM_NT);
  int* te     = (int*)(sm + SM_TE);
  int* trs    = (int*)(sm + SM_TRS);
  int* e01    = (int*)(sm + SM_E01);
  float* w01  = (float*)(sm + SM_W01);
  int* atok   = (int*)(sm + SM_ATOK);
  float* aw   = (float*)(sm + SM_AW);
  int* slots  = (int*)(sm + SM_SLOT);

  init_k<<<1, 64, 0, stream>>>(counts, fill, invt);
  wsplit2_k<<<dim3(96,64,2), 256, 0, stream>>>(Wqkv, qkvTh, qkvTl, Wout, woutTh, woutTl);
  ln1_k<<<S_LEN, 256, 0, stream>>>(hidden, ln1w, ln1b, h1h, h1l);
  gemm32_k<0><<<dim3(48,16), 256, 0, stream>>>(h1h, h1l, qkvTh, qkvTl, qkv, nullptr);
  ropevt_k<<<S_LEN + 1024, 256, 0, stream>>>(qkv, pos, invt, Qh, Ql, Kh, Kl, Vth, Vtl);
  attn_k<<<768, 256, 0, stream>>>(Qh, Ql, Kh, Kl, Vth, Vtl, Oh, Ol, Opart, Mlp);
  merge_k<<<dim3(16,16), 256, 0, stream>>>(Opart, Mlp, Oh, Ol);
  gemm32_k<1><<<dim3(32,16), 256, 0, stream>>>(Oh, Ol, woutTh, woutTl, h2, hidden);
  ln2_router_k<<<S_LEN, 256, 0, stream>>>(h2, ln2w, ln2b, Wr, x2, e01, w01, counts);
  htiles_k<<<1, 64, 0, stream>>>(counts, offs, ntl, te, trs);
  scatter_k<<<8, 256, 0, stream>>>(e01, w01, offs, fill, atok, aw, slots);
  if (ws_size >= WS_BIG){
    wconvT2_k<<<dim3(32,32,16), 256, 0, stream>>>(w1, wT0, v1, wT1);
    gemm_moe13_k<<<dim3(16,40), 512, 0, stream>>>(x2, wT0, wT1, Yb,
        atok, counts, offs, ntl, te, trs);
    wconvT_k<<<dim3(32,32,8), 256, 0, stream>>>(w2, wT0);
    gemm_moe_k<4><<<dim3(32,40), 256, 0, stream>>>(Yb, wT0, moe, nullptr, aw,
        atok, counts, offs, ntl, te, trs);
  } else {
    wconvT_k<<<dim3(32,32,8), 256, 0, stream>>>(w1, wT0);
    gemm_moe_k<2><<<dim3(32,40), 256, 0, stream>>>(x2, wT0, i1, nullptr, nullptr,
        atok, counts, offs, ntl, te, trs);
    wconvT_k<<<dim3(32,32,8), 256, 0, stream>>>(v1, wT0);
    gemm_moe_k<3><<<dim3(32,40), 256, 0, stream>>>(x2, wT0, Yb, i1, nullptr,
        atok, counts, offs, ntl, te, trs);
    wconvT_k<<<dim3(32,32,8), 256, 0, stream>>>(w2, wT0);
    gemm_moe_k<4><<<dim3(32,40), 256, 0, stream>>>(Yb, wT0, moe, nullptr, aw,
        atok, counts, offs, ntl, te, trs);
  }
  combine_k<<<S_LEN, 256, 0, stream>>>(h2, moe, slots, out);
}

// Round 15
// 672.389 us; speedup vs baseline: 2.1369x; 2.1369x over previous
//
#include <hip/hip_runtime.h>
#include <cstdint>
#include <cstddef>
#include <cmath>

typedef unsigned short u16;
typedef unsigned int u32;
typedef __attribute__((ext_vector_type(8))) _Float16 f16x8;
typedef __attribute__((ext_vector_type(4))) float f32x4;

#define S_LEN 2048
#define DMODEL 2048
#define NHEAD 16
#define NKVH 4
#define HDIM 128
#define NQKV 3072
#define NF 2048
#define TA 4096
#define ATT_SCALE 0.08838834764831845f
#define LO_SCALE 1024.0f
#define LO_INV (1.0f/1024.0f)
#define DEFER_THR 8.0f

static __device__ __forceinline__ u16 f2h(float x){ _Float16 h=(_Float16)x; return __builtin_bit_cast(u16,h); }
static __device__ __forceinline__ float h2f(u16 u){ return (float)__builtin_bit_cast(_Float16,u); }
static __device__ __forceinline__ void split2(float x, u16& hi, u16& lo){
  hi = f2h(x);
  lo = f2h((x - h2f(hi)) * LO_SCALE);
}
// async global->LDS, 16B per lane; LDS dest = wave-uniform base + lane*16
static __device__ __forceinline__ void gload16(const u16* g, u16* l){
  __builtin_amdgcn_global_load_lds(
      (const __attribute__((address_space(1))) void*)g,
      (__attribute__((address_space(3))) void*)l, 16, 0, 0);
}
// XCD-aware block swizzle (requires nwg % 8 == 0)
static __device__ __forceinline__ void xcd_swz(int& bx, int& by){
  int gx = gridDim.x;
  int n = gx * gridDim.y;
  int bid = by*gx + bx;
  int cpx = n >> 3;
  int s = (bid & 7)*cpx + (bid >> 3);
  bx = s % gx; by = s / gx;
}

// ---------------- static attn work-item table (rank-sorted descending by size) ----------
__constant__ int c_itq[48] = {
  15,31,31,30,30,14,29,29,28,28,13,27,27,26,26,12,25,25,24,24,
  11,23,23,22,22,10,21,21,20,20, 9,19,19,18,18, 8,17,17,16,16,
   7, 6, 5, 4, 3, 2, 1, 0};
__constant__ int c_itk0[48] = {
   0, 0,32, 0,31, 0, 0,30, 0,29, 0, 0,28, 0,27, 0, 0,26, 0,25,
   0, 0,24, 0,23, 0, 0,22, 0,21, 0, 0,20, 0,19, 0, 0,18, 0,17,
   0, 0, 0, 0, 0, 0, 0, 0};
__constant__ int c_itk1[48] = {
  32,32,64,31,62,30,30,60,29,58,28,28,56,27,54,26,26,52,25,50,
  24,24,48,23,46,22,22,44,21,42,20,20,40,19,38,18,18,36,17,34,
  16,14,12,10, 8, 6, 4, 2};
__constant__ int c_itsl[48] = {
  -1,30,31,28,29,-1,26,27,24,25,-1,22,23,20,21,-1,18,19,16,17,
  -1,14,15,12,13,-1,10,11, 8, 9,-1, 6, 7, 4, 5,-1, 2, 3, 0, 1,
  -1,-1,-1,-1,-1,-1,-1,-1};

// ---------------- workspace layout (bytes) ----------------
#define WS_WOUTH ((size_t)0)
#define WS_WOUTL ((size_t)8388608)
#define WS_QKVTH ((size_t)16777216)
#define WS_QKVTL ((size_t)29360128)
#define WS_H1H   ((size_t)41943040)
#define WS_H1L   ((size_t)50331648)
#define WS_QKV   ((size_t)58720256)
#define WS_QH    ((size_t)16777216)
#define WS_QL    ((size_t)25165824)
#define WS_KH    ((size_t)33554432)
#define WS_KL    ((size_t)35651584)
#define WS_VTH   ((size_t)37748736)
#define WS_VTL   ((size_t)39845888)
#define WS_OH    ((size_t)41943040)
#define WS_OL    ((size_t)50331648)
#define WS_H2    ((size_t)58720256)
#define WS_X2    ((size_t)75497472)
#define WS_I1    ((size_t)0)
#define WS_Y     ((size_t)16777216)
#define WS_MOE   ((size_t)33554432)
#define WS_SM    ((size_t)83886080)
#define WS_WT0   ((size_t)84934656)
#define WS_WT1   ((size_t)152043520)
#define WS_BIG   ((size_t)219152384)
#define SM_INVT   0
#define SM_COUNTS 256
#define SM_FILL   320
#define SM_OFFS   384
#define SM_NT     448
#define SM_TE     512
#define SM_TRS    768
#define SM_E01    1024
#define SM_W01    (1024+16384)
#define SM_ATOK   (1024+2*16384)
#define SM_AW     (1024+3*16384)
#define SM_SLOT   (1024+4*16384)

// ---------------- init ----------------
__global__ void __launch_bounds__(64) init_k(int* counts, int* fill, float* invt){
  int t = threadIdx.x;
  if (t < 8) { counts[t] = 0; fill[t] = 0; }
  double di = (double)t * (1.0/64.0);
  float y = (float)pow(500000.0, di);
  invt[t] = 1.0f / y;
}

// ---------------- weight split+transpose, merged: z=0 -> Wqkv, z=1 -> Wout ----------------
__global__ void __launch_bounds__(256) wsplit2_k(
    const float* __restrict__ Wq, u16* __restrict__ Tqh, u16* __restrict__ Tql,
    const float* __restrict__ Wo, u16* __restrict__ Toh, u16* __restrict__ Tol){
  __shared__ float tile[32][33];
  int z = blockIdx.z;
  int N = z ? DMODEL : NQKV;
  if (z && blockIdx.x >= 64) return;
  const float* W = z ? Wo : Wq;
  u16* Th = z ? Toh : Tqh;
  u16* Tl = z ? Tol : Tql;
  int n0 = blockIdx.x*32, k0 = blockIdx.y*32;
  int tid = threadIdx.x;
  int rr = tid >> 3, cg = tid & 7;
  #pragma unroll
  for (int j=0;j<4;++j)
    tile[rr][cg*4+j] = W[(size_t)(k0+rr)*N + n0 + cg*4 + j];
  __syncthreads();
  int cc = tid >> 3, sg = tid & 7;
  #pragma unroll
  for (int j=0;j<4;++j){
    float x = tile[sg*4+j][cc];
    u16 hi, lo; split2(x, hi, lo);
    size_t idx = (size_t)(n0+cc)*2048 + k0 + sg*4 + j;
    Th[idx] = hi; Tl[idx] = lo;
  }
}

// ---------------- MoE weight convert+transpose: fp32 [e][k][n] -> f16 [e][n][k] ----------------
// Merged dual-weight variant: z=0..7 -> (Wa -> Ta), z=8..15 -> (Wb -> Tb)
__global__ void __launch_bounds__(256) wconvT2_k(const float* __restrict__ Wa,
    u16* __restrict__ Ta, const float* __restrict__ Wb, u16* __restrict__ Tb){
  __shared__ float tile[64][68];
  int z = blockIdx.z;
  const float* W = (z < 8) ? Wa : Wb;
  u16* T = (z < 8) ? Ta : Tb;
  int e = z & 7;
  int n0 = blockIdx.x*64, k0 = blockIdx.y*64;
  size_t ebase = (size_t)e * 2048 * 2048;
  int tid = threadIdx.x;
  int rr = tid >> 4, c4 = (tid & 15)*4;
  #pragma unroll
  for (int p=0;p<4;++p){
    float4 v = *(const float4*)(W + ebase + (size_t)(k0+p*16+rr)*2048 + n0 + c4);
    *(float4*)&tile[p*16+rr][c4] = v;
  }
  __syncthreads();
  int nn = tid >> 2, kc = (tid & 3)*16;
  u16 buf[16];
  #pragma unroll
  for (int j=0;j<16;++j) buf[j] = f2h(tile[kc+j][nn]);
  u16* dst = T + ebase + (size_t)(n0+nn)*2048 + k0 + kc;
  *(int4*)dst = *(int4*)&buf[0];
  *(int4*)(dst+8) = *(int4*)&buf[8];
}

// single-weight variant (w2, reuses wT0 after moe13)
__global__ void __launch_bounds__(256) wconvT_k(const float* __restrict__ W,
                                                u16* __restrict__ T){
  __shared__ float tile[64][68];
  int n0 = blockIdx.x*64, k0 = blockIdx.y*64;
  size_t ebase = (size_t)blockIdx.z * 2048 * 2048;
  int tid = threadIdx.x;
  int rr = tid >> 4, c4 = (tid & 15)*4;
  #pragma unroll
  for (int p=0;p<4;++p){
    float4 v = *(const float4*)(W + ebase + (size_t)(k0+p*16+rr)*2048 + n0 + c4);
    *(float4*)&tile[p*16+rr][c4] = v;
  }
  __syncthreads();
  int nn = tid >> 2, kc = (tid & 3)*16;
  u16 buf[16];
  #pragma unroll
  for (int j=0;j<16;++j) buf[j] = f2h(tile[kc+j][nn]);
  u16* dst = T + ebase + (size_t)(n0+nn)*2048 + k0 + kc;
  *(int4*)dst = *(int4*)&buf[0];
  *(int4*)(dst+8) = *(int4*)&buf[8];
}

__device__ __forceinline__ float blk_red_sum(float v, float* red, int tid){
  #pragma unroll
  for (int off=1; off<64; off<<=1) v += __shfl_xor(v, off);
  if ((tid&63)==0) red[tid>>6] = v;
  __syncthreads();
  float r = red[0]+red[1]+red[2]+red[3];
  __syncthreads();
  return r;
}

// ---------------- LN1 -> split planes ----------------
__global__ void __launch_bounds__(256) ln1_k(const float* __restrict__ X,
    const float* __restrict__ W, const float* __restrict__ Bv,
    u16* __restrict__ Hh, u16* __restrict__ Hl){
  __shared__ float red[4];
  int t = blockIdx.x, tid = threadIdx.x;
  const float* row = X + (size_t)t*DMODEL + tid*8;
  float4 a = *(const float4*)row;
  float4 b = *(const float4*)(row+4);
  float xs[8] = {a.x,a.y,a.z,a.w,b.x,b.y,b.z,b.w};
  float s = 0.f;
  #pragma unroll
  for (int j=0;j<8;++j) s += xs[j];
  float mu = blk_red_sum(s, red, tid) * (1.f/DMODEL);
  float sq = 0.f;
  #pragma unroll
  for (int j=0;j<8;++j){ float d = xs[j]-mu; sq += d*d; }
  float var = blk_red_sum(sq, red, tid) * (1.f/DMODEL);
  float rs = 1.0f/sqrtf(var + 1e-5f);
  float4 w0 = *(const float4*)(W + tid*8);
  float4 w1 = *(const float4*)(W + tid*8 + 4);
  float4 b0 = *(const float4*)(Bv + tid*8);
  float4 b1 = *(const float4*)(Bv + tid*8 + 4);
  float ws_[8] = {w0.x,w0.y,w0.z,w0.w,w1.x,w1.y,w1.z,w1.w};
  float bs_[8] = {b0.x,b0.y,b0.z,b0.w,b1.x,b1.y,b1.z,b1.w};
  u32 ph[4], pl[4];
  #pragma unroll
  for (int j=0;j<4;++j){
    u16 h0,l0,h1,l1;
    split2((xs[2*j]-mu)*rs*ws_[2*j]+bs_[2*j], h0, l0);
    split2((xs[2*j+1]-mu)*rs*ws_[2*j+1]+bs_[2*j+1], h1, l1);
    ph[j] = (u32)h0 | ((u32)h1<<16);
    pl[j] = (u32)l0 | ((u32)l1<<16);
  }
  int4 vh; vh.x=(int)ph[0]; vh.y=(int)ph[1]; vh.z=(int)ph[2]; vh.w=(int)ph[3];
  int4 vl; vl.x=(int)pl[0]; vl.y=(int)pl[1]; vl.z=(int)pl[2]; vl.w=(int)pl[3];
  *(int4*)(Hh + (size_t)t*DMODEL + tid*8) = vh;
  *(int4*)(Hl + (size_t)t*DMODEL + tid*8) = vl;
}

// ---------------- split-precision GEMM, 128(M)x64(N) tile, BK=64 ----------------
template<int MODE>
__global__ void __launch_bounds__(256) gemm32_k(
    const u16* __restrict__ Ahp, const u16* __restrict__ Alp,
    const u16* __restrict__ Bhp, const u16* __restrict__ Blp,
    float* __restrict__ C, const float* __restrict__ res)
{
  constexpr int K = 2048;
  __shared__ u16 Ash[128*64], Asl[128*64], Bsh[64*64], Bsl[64*64];
  int bx = blockIdx.x, by = blockIdx.y;
  xcd_swz(bx, by);
  int m0 = by*128, n0 = bx*64;
  int tid = threadIdx.x, w = tid>>6, lane = tid&63;
  int l15 = lane&15, l4 = lane>>4, wr = w>>1, wc = w&1;
  int srow8 = lane >> 3;
  int sslot = ((lane&7) ^ srow8) * 8;

  f32x4 accH[4][2] = {}, accC[4][2] = {};

  for (int k0 = 0; k0 < K; k0 += 64){
    __syncthreads();
    #pragma unroll
    for (int c=0;c<4;++c){
      int row = w*32 + c*8 + srow8;
      size_t ga = (size_t)(m0+row)*K + k0 + sslot;
      gload16(Ahp+ga, &Ash[(w*32+c*8)*64]);
      gload16(Alp+ga, &Asl[(w*32+c*8)*64]);
    }
    #pragma unroll
    for (int c=0;c<2;++c){
      int rowb = w*16 + c*8 + srow8;
      size_t gb = (size_t)(n0+rowb)*K + k0 + sslot;
      gload16(Bhp+gb, &Bsh[(w*16+c*8)*64]);
      gload16(Blp+gb, &Bsl[(w*16+c*8)*64]);
    }
    __syncthreads();
    #pragma unroll
    for (int kk=0; kk<2; ++kk){
      int xslot = ((kk*4 + l4) ^ (l15 & 7)) * 8;
      f16x8 ah[4], al[4];
      #pragma unroll
      for (int mi=0; mi<4; ++mi){
        int row = wr*64 + mi*16 + l15;
        ah[mi] = *(const f16x8*)&Ash[row*64 + xslot];
        al[mi] = *(const f16x8*)&Asl[row*64 + xslot];
      }
      #pragma unroll
      for (int ni=0; ni<2; ++ni){
        int row = wc*32 + ni*16 + l15;
        f16x8 bh = *(const f16x8*)&Bsh[row*64 + xslot];
        f16x8 bl = *(const f16x8*)&Bsl[row*64 + xslot];
        #pragma unroll
        for (int mi=0; mi<4; ++mi){
          accH[mi][ni] = __builtin_amdgcn_mfma_f32_16x16x32_f16(ah[mi], bh, accH[mi][ni], 0,0,0);
          accC[mi][ni] = __builtin_amdgcn_mfma_f32_16x16x32_f16(ah[mi], bl, accC[mi][ni], 0,0,0);
          accC[mi][ni] = __builtin_amdgcn_mfma_f32_16x16x32_f16(al[mi], bh, accC[mi][ni], 0,0,0);
        }
      }
    }
  }

  #pragma unroll
  for (int mi=0; mi<4; ++mi){
    #pragma unroll
    for (int ni=0; ni<2; ++ni){
      #pragma unroll
      for (int r=0; r<4; ++r){
        int rl = wr*64 + mi*16 + l4*4 + r;
        int cl = wc*32 + ni*16 + l15;
        float v = accH[mi][ni][r] + accC[mi][ni][r]*LO_INV;
        if constexpr (MODE == 0){
          v = fminf(fmaxf(v, -8.f), 8.f);
          C[(size_t)(m0 + rl)*NQKV + n0 + cl] = v;
        } else {
          size_t idx = (size_t)(m0 + rl)*DMODEL + n0 + cl;
          C[idx] = v + res[idx];
        }
      }
    }
  }
}

// ---------------- merged RoPE + V-transpose (both read qkv only) ----------------
__global__ void __launch_bounds__(256) ropevt_k(const float* __restrict__ qkv,
    const int* __restrict__ pos_ids, const float* __restrict__ invt,
    u16* __restrict__ Qh, u16* __restrict__ Ql, u16* __restrict__ Kh, u16* __restrict__ Kl,
    u16* __restrict__ Vth, u16* __restrict__ Vtl){
  __shared__ float tile[32][33];
  int bid = blockIdx.x;
  int tid = threadIdx.x;
  if (bid < S_LEN){
    int s = bid;
    float pos = (float)pos_ids[s];
    const float* row = qkv + (size_t)s*NQKV;
    for (int p = tid; p < 1280; p += 256){
      int i = p & 63;
      float ang = pos * invt[i];
      float sn, cs;
      sincosf(ang, &sn, &cs);
      u16 h1_,l1_,h2_,l2_;
      if (p < 1024){
        int h = p >> 6;
        float x1 = row[h*HDIM + i];
        float x2 = row[h*HDIM + 64 + i];
        size_t base = ((size_t)h*S_LEN + s)*HDIM;
        split2(x1*cs - x2*sn, h1_, l1_);
        split2(x2*cs + x1*sn, h2_, l2_);
        Qh[base + i] = h1_; Ql[base + i] = l1_;
        Qh[base + 64 + i] = h2_; Ql[base + 64 + i] = l2_;
      } else {
        int kh = (p-1024) >> 6;
        float x1 = row[2048 + kh*HDIM + i];
        float x2 = row[2048 + kh*HDIM + 64 + i];
        size_t base = ((size_t)kh*S_LEN + s)*HDIM;
        split2(x1*cs - x2*sn, h1_, l1_);
        split2(x2*cs + x1*sn, h2_, l2_);
        Kh[base + i] = h1_; Kl[base + i] = l1_;
        Kh[base + 64 + i] = h2_; Kl[base + 64 + i] = l2_;
      }
    }
  } else {
    int t = bid - S_LEN;            // 0..1023
    int s0 = (t & 63)*32, c0 = (t >> 6)*32;
    int rr = tid >> 3, cg = tid & 7;
    #pragma unroll
    for (int j=0;j<4;++j)
      tile[rr][cg*4+j] = qkv[(size_t)(s0+rr)*NQKV + 2560 + c0 + cg*4 + j];
    __syncthreads();
    int cc = tid >> 3, sg = tid & 7;
    #pragma unroll
    for (int j=0;j<4;++j){
      float x = tile[sg*4+j][cc];
      u16 hi, lo; split2(x, hi, lo);
      size_t idx = (size_t)(c0+cc)*S_LEN + s0 + sg*4 + j;
      Vth[idx] = hi; Vtl[idx] = lo;
    }
  }
}

// ---------------- flash attention (split precision, deferred max, KV-split items) ----------------
__global__ void __launch_bounds__(256, 3) attn_k(
    const u16* __restrict__ Qhp, const u16* __restrict__ Qlp,
    const u16* __restrict__ Khp, const u16* __restrict__ Klp,
    const u16* __restrict__ Vthp, const u16* __restrict__ Vtlp,
    u16* __restrict__ Oh, u16* __restrict__ Ol,
    float* __restrict__ Opart, float* __restrict__ Mlp){
  __shared__ u16 Ksh[32*128], Ksl[32*128];
  __shared__ u16 Vsh[128*32], Vsl[128*32];
  __shared__ u16 Psh[4*16*40], Psl[4*16*40];
  int tid = threadIdx.x;
  int w = tid>>6, lane = tid&63, l15 = lane&15, l4 = lane>>4;
  int rank = blockIdx.x >> 4, h = blockIdx.x & 15, kvh = h >> 2;
  int qb = c_itq[rank], kb0 = c_itk0[rank], kb1 = c_itk1[rank], sl = c_itsl[rank];
  int q0 = qb*64 + w*16;
  f16x8 qfh[4], qfl[4];
  #pragma unroll
  for (int ds=0; ds<4; ++ds){
    size_t off = ((size_t)h*S_LEN + q0 + l15)*HDIM + ds*32 + l4*8;
    qfh[ds] = *(const f16x8*)(Qhp + off);
    qfl[ds] = *(const f16x8*)(Qlp + off);
  }
  f32x4 accH[8] = {}, accC[8] = {};
  float m_r[4], l_r[4];
  #pragma unroll
  for (int r=0;r<4;++r){ m_r[r] = -1e30f; l_r[r] = 0.f; }
  for (int kb = kb0; kb < kb1; ++kb){
    int kbase = kb*32;
    __syncthreads();
    #pragma unroll
    for (int c=0;c<2;++c){
      int krow = w*8 + c*4 + l4;
      int ks = l15;
      int kcol = ((ks&8) | ((ks&7) ^ (krow&7)))*8;
      size_t koff = ((size_t)kvh*S_LEN + kbase + krow)*HDIM + kcol;
      gload16(Khp + koff, &Ksh[(w*8+c*4)*128]);
      gload16(Klp + koff, &Ksl[(w*8+c*4)*128]);
      int vrow = w*32 + c*16 + (lane>>2);
      int vcol = ((lane&3) ^ ((lane>>3)&3))*8;
      size_t voff = ((size_t)kvh*HDIM + vrow)*S_LEN + kbase + vcol;
      gload16(Vthp + voff, &Vsh[(w*32+c*16)*32]);
      gload16(Vtlp + voff, &Vsl[(w*32+c*16)*32]);
    }
    __syncthreads();
    // QK^T
    f32x4 sH0 = {}, sH1 = {}, sC0 = {}, sC1 = {};
    __builtin_amdgcn_s_setprio(1);
    #pragma unroll
    for (int ds=0; ds<4; ++ds){
      int ksl = ds*4 + l4;
      int klds = ((ksl&8) | ((ksl&7) ^ (l15&7)))*8;
      f16x8 kh0 = *(const f16x8*)&Ksh[l15*128 + klds];
      f16x8 kl0 = *(const f16x8*)&Ksl[l15*128 + klds];
      f16x8 kh1 = *(const f16x8*)&Ksh[(16+l15)*128 + klds];
      f16x8 kl1 = *(const f16x8*)&Ksl[(16+l15)*128 + klds];
      sH0 = __builtin_amdgcn_mfma_f32_16x16x32_f16(qfh[ds], kh0, sH0, 0,0,0);
      sC0 = __builtin_amdgcn_mfma_f32_16x16x32_f16(qfh[ds], kl0, sC0, 0,0,0);
      sC0 = __builtin_amdgcn_mfma_f32_16x16x32_f16(qfl[ds], kh0, sC0, 0,0,0);
      sH1 = __builtin_amdgcn_mfma_f32_16x16x32_f16(qfh[ds], kh1, sH1, 0,0,0);
      sC1 = __builtin_amdgcn_mfma_f32_16x16x32_f16(qfh[ds], kl1, sC1, 0,0,0);
      sC1 = __builtin_amdgcn_mfma_f32_16x16x32_f16(qfl[ds], kh1, sC1, 0,0,0);
    }
    __builtin_amdgcn_s_setprio(0);
    // softmax with deferred max (THR=8)
    float v0[4], v1[4];
    bool need = false;
    #pragma unroll
    for (int r=0;r<4;++r){
      int qg = q0 + l4*4 + r;
      v0[r] = (sH0[r] + sC0[r]*LO_INV)*ATT_SCALE; if (kbase + l15 > qg) v0[r] = -1e9f;
      v1[r] = (sH1[r] + sC1[r]*LO_INV)*ATT_SCALE; if (kbase + 16 + l15 > qg) v1[r] = -1e9f;
      float pm = fmaxf(v0[r], v1[r]);
      need = need || (pm > m_r[r] + DEFER_THR);
    }
    if (__any(need)){
      float fac[4];
      #pragma unroll
      for (int r=0;r<4;++r){
        float mx = fmaxf(v0[r], v1[r]);
        mx = fmaxf(mx, __shfl_xor(mx,1));
        mx = fmaxf(mx, __shfl_xor(mx,2));
        mx = fmaxf(mx, __shfl_xor(mx,4));
        mx = fmaxf(mx, __shfl_xor(mx,8));
        float mnew = fmaxf(m_r[r], mx);
        fac[r] = __expf(m_r[r] - mnew);
        l_r[r] *= fac[r];
        m_r[r] = mnew;
      }
      #pragma unroll
      for (int nt=0; nt<8; ++nt){
        #pragma unroll
        for (int r=0;r<4;++r){ accH[nt][r] *= fac[r]; accC[nt][r] *= fac[r]; }
      }
    }
    #pragma unroll
    for (int r=0;r<4;++r){
      float p0 = __expf(v0[r] - m_r[r]);
      float p1 = __expf(v1[r] - m_r[r]);
      l_r[r] += p0 + p1;
      u16 hi, lo;
      split2(p0, hi, lo);
      Psh[w*640 + (l4*4+r)*40 + l15] = hi;
      Psl[w*640 + (l4*4+r)*40 + l15] = lo;
      split2(p1, hi, lo);
      Psh[w*640 + (l4*4+r)*40 + 16 + l15] = hi;
      Psl[w*640 + (l4*4+r)*40 + 16 + l15] = lo;
    }
    // P is wave-private LDS: program order + lgkmcnt suffice
    f16x8 pfh = *(const f16x8*)&Psh[w*640 + l15*40 + l4*8];
    f16x8 pfl = *(const f16x8*)&Psl[w*640 + l15*40 + l4*8];
    __builtin_amdgcn_s_setprio(1);
    #pragma unroll
    for (int nt=0; nt<8; ++nt){
      int vsl = (l4 ^ ((l15>>1)&3))*8;
      f16x8 vh = *(const f16x8*)&Vsh[(nt*16 + l15)*32 + vsl];
      f16x8 vl = *(const f16x8*)&Vsl[(nt*16 + l15)*32 + vsl];
      accH[nt] = __builtin_amdgcn_mfma_f32_16x16x32_f16(pfh, vh, accH[nt], 0,0,0);
      f32x4 aC = __builtin_amdgcn_mfma_f32_16x16x32_f16(pfh, vl, accC[nt], 0,0,0);
      accC[nt] = __builtin_amdgcn_mfma_f32_16x16x32_f16(pfl, vh, aC, 0,0,0);
    }
    __builtin_amdgcn_s_setprio(0);
  }
  // final l reduction over the 16 k-lanes
  #pragma unroll
  for (int r=0;r<4;++r){
    float l = l_r[r];
    l += __shfl_xor(l,1); l += __shfl_xor(l,2);
    l += __shfl_xor(l,4); l += __shfl_xor(l,8);
    l_r[r] = l;
  }
  if (sl < 0){
    #pragma unroll
    for (int nt=0; nt<8; ++nt){
      #pragma unroll
      for (int r=0;r<4;++r){
        int row = q0 + l4*4 + r;
        int col = h*HDIM + nt*16 + l15;
        float val = (accH[nt][r] + accC[nt][r]*LO_INV) / l_r[r];
        u16 hi, lo; split2(val, hi, lo);
        Oh[(size_t)row*DMODEL + col] = hi;
        Ol[(size_t)row*DMODEL + col] = lo;
      }
    }
  } else {
    int slot = sl*16 + h;
    float* Op = Opart + (size_t)slot*8192;
    #pragma unroll
    for (int nt=0; nt<8; ++nt){
      #pragma unroll
      for (int r=0;r<4;++r){
        int row = w*16 + l4*4 + r;
        Op[row*128 + nt*16 + l15] = accH[nt][r] + accC[nt][r]*LO_INV;
      }
    }
    if (l15 == 0){
      #pragma unroll
      for (int r=0;r<4;++r){
        int row = w*16 + l4*4 + r;
        Mlp[slot*128 + row*2]     = m_r[r];
        Mlp[slot*128 + row*2 + 1] = l_r[r];
      }
    }
  }
}

// ---------------- merge two KV-half partials -> Oh/Ol ----------------
__global__ void __launch_bounds__(256) merge_k(const float* __restrict__ Op,
    const float* __restrict__ Ml, u16* __restrict__ Oh, u16* __restrict__ Ol){
  int qb = 16 + blockIdx.x, h = blockIdx.y;
  int slot1 = ((qb-16)*2)*16 + h;
  int slot2 = slot1 + 16;
  int tid = threadIdx.x;
  int rr = tid >> 2, cg = (tid & 3) * 32;
  float m1 = Ml[slot1*128 + rr*2], l1 = Ml[slot1*128 + rr*2 + 1];
  float m2 = Ml[slot2*128 + rr*2], l2 = Ml[slot2*128 + rr*2 + 1];
  float M = fmaxf(m1, m2);
  float a1 = __expf(m1 - M), a2 = __expf(m2 - M);
  float inv = 1.f / (l1*a1 + l2*a2);
  const float* p1 = Op + (size_t)slot1*8192 + rr*128 + cg;
  const float* p2 = Op + (size_t)slot2*8192 + rr*128 + cg;
  size_t ob = (size_t)(qb*64 + rr)*DMODEL + h*HDIM + cg;
  #pragma unroll
  for (int j = 0; j < 32; j += 4){
    float4 o1 = *(const float4*)(p1 + j);
    float4 o2 = *(const float4*)(p2 + j);
    float vals[4] = {(o1.x*a1+o2.x*a2)*inv, (o1.y*a1+o2.y*a2)*inv,
                     (o1.z*a1+o2.z*a2)*inv, (o1.w*a1+o2.w*a2)*inv};
    u16 hs[4], ls[4];
    #pragma unroll
    for (int c=0;c<4;++c) split2(vals[c], hs[c], ls[c]);
    *(uint2*)(Oh + ob + j) = *(uint2*)&hs[0];
    *(uint2*)(Ol + ob + j) = *(uint2*)&ls[0];
  }
}

// ---------------- LN2 + router ----------------
__global__ void __launch_bounds__(256) ln2_router_k(const float* __restrict__ H2,
    const float* __restrict__ W, const float* __restrict__ Bv,
    const float* __restrict__ Wr, u16* __restrict__ X2,
    int* __restrict__ e01, float* __restrict__ w01, int* __restrict__ counts){
  __shared__ float red[4];
  __shared__ float lred[4][8];
  int t = blockIdx.x, tid = threadIdx.x;
  const float* row = H2 + (size_t)t*DMODEL + tid*8;
  float4 a = *(const float4*)row;
  float4 b = *(const float4*)(row+4);
  float xs[8] = {a.x,a.y,a.z,a.w,b.x,b.y,b.z,b.w};
  float s = 0.f;
  #pragma unroll
  for (int j=0;j<8;++j) s += xs[j];
  float mu = blk_red_sum(s, red, tid) * (1.f/DMODEL);
  float sq = 0.f;
  #pragma unroll
  for (int j=0;j<8;++j){ float d = xs[j]-mu; sq += d*d; }
  float var = blk_red_sum(sq, red, tid) * (1.f/DMODEL);
  float rs = 1.0f/sqrtf(var + 1e-5f);
  float4 w0 = *(const float4*)(W + tid*8);
  float4 w1 = *(const float4*)(W + tid*8 + 4);
  float4 b0 = *(const float4*)(Bv + tid*8);
  float4 b1 = *(const float4*)(Bv + tid*8 + 4);
  float ws_[8] = {w0.x,w0.y,w0.z,w0.w,w1.x,w1.y,w1.z,w1.w};
  float bs_[8] = {b0.x,b0.y,b0.z,b0.w,b1.x,b1.y,b1.z,b1.w};
  float xn[8];
  #pragma unroll
  for (int j=0;j<8;++j) xn[j] = (xs[j]-mu)*rs*ws_[j]+bs_[j];
  u32 pk[4];
  #pragma unroll
  for (int j=0;j<4;++j) pk[j] = (u32)f2h(xn[2*j]) | ((u32)f2h(xn[2*j+1])<<16);
  int4 v; v.x=(int)pk[0]; v.y=(int)pk[1]; v.z=(int)pk[2]; v.w=(int)pk[3];
  *(int4*)(X2 + (size_t)t*DMODEL + tid*8) = v;
  float lg[8] = {0,0,0,0,0,0,0,0};
  #pragma unroll
  for (int j=0;j<8;++j){
    const float* wrp = Wr + (size_t)(tid*8 + j)*8;
    float4 wa = *(const float4*)wrp;
    float4 wb = *(const float4*)(wrp+4);
    lg[0]+=xn[j]*wa.x; lg[1]+=xn[j]*wa.y; lg[2]+=xn[j]*wa.z; lg[3]+=xn[j]*wa.w;
    lg[4]+=xn[j]*wb.x; lg[5]+=xn[j]*wb.y; lg[6]+=xn[j]*wb.z; lg[7]+=xn[j]*wb.w;
  }
  #pragma unroll
  for (int e=0;e<8;++e){
    #pragma unroll
    for (int off=1; off<64; off<<=1) lg[e] += __shfl_xor(lg[e], off);
  }
  if ((tid&63)==0){
    #pragma unroll
    for (int e=0;e<8;++e) lred[tid>>6][e] = lg[e];
  }
  __syncthreads();
  if (tid==0){
    float L[8];
    #pragma unroll
    for (int e=0;e<8;++e) L[e] = lred[0][e]+lred[1][e]+lred[2][e]+lred[3][e];
    int e0 = 0;
    #pragma unroll
    for (int e=1;e<8;++e) if (L[e] > L[e0]) e0 = e;
    int e1 = (e0==0)?1:0;
    #pragma unroll
    for (int e=0;e<8;++e) if (e!=e0 && L[e] > L[e1]) e1 = e;
    float ax = expf(L[e1]-L[e0]);
    float z = 1.f/(1.f+ax);
    e01[2*t] = e0; e01[2*t+1] = e1;
    w01[2*t] = z;  w01[2*t+1] = ax*z;
    atomicAdd(&counts[e0],1); atomicAdd(&counts[e1],1);
  }
}

__global__ void __launch_bounds__(64) htiles_k(const int* counts, int* offs, int* ntl,
                                               int* te, int* trs){
  if (threadIdx.x==0){
    int off=0;
    for (int e=0;e<8;++e){ offs[e]=off; off+=counts[e]; }
    offs[8]=off;
    int nt=0;
    for (int e=0;e<8;++e)
      for (int j=0; j*128 < counts[e]; ++j){ te[nt]=e; trs[nt]=j*128; nt++; }
    ntl[0]=nt;
  }
}

__global__ void __launch_bounds__(256) scatter_k(const int* __restrict__ e01,
    const float* __restrict__ w01, const int* __restrict__ offs, int* __restrict__ fill,
    int* __restrict__ atok, float* __restrict__ aw, int* __restrict__ slots){
  int t = blockIdx.x*256 + threadIdx.x;
  if (t >= S_LEN) return;
  int e0 = e01[2*t], e1 = e01[2*t+1];
  int p0 = offs[e0] + atomicAdd(&fill[e0],1);
  atok[p0] = t; aw[p0] = w01[2*t]; slots[2*t] = p0;
  int p1 = offs[e1] + atomicAdd(&fill[e1],1);
  atok[p1] = t; aw[p1] = w01[2*t+1]; slots[2*t+1] = p1;
}

// ---------------- fused grouped GEMM: Y = silu(x@w1)*(x@v1), 128x64 tile, BK=64 ----------------
// (R13-proven form: 256 threads, VGPR 84, no spill, 5 blocks/CU)
__global__ void __launch_bounds__(256) gemm_moe13_k(
    const u16* __restrict__ A, const u16* __restrict__ B1T, const u16* __restrict__ B2T,
    u16* __restrict__ Y,
    const int* __restrict__ atok, const int* __restrict__ counts,
    const int* __restrict__ offs, const int* __restrict__ ntl,
    const int* __restrict__ te, const int* __restrict__ trs)
{
  constexpr int K = 2048;
  __shared__ u16 As[128*64], B1s[64*64], B2s[64*64];
  int bx = blockIdx.x, by = blockIdx.y;
  xcd_swz(bx, by);
  if (by >= ntl[0]) return;
  int e = te[by];
  int rsu = trs[by];
  int base = offs[e] + rsu;
  int valid = min(128, counts[e] - rsu);
  const u16* B1p = B1T + (size_t)e * 2048 * 2048;
  const u16* B2p = B2T + (size_t)e * 2048 * 2048;
  int tid = threadIdx.x, w = tid>>6, lane = tid&63;
  int l15 = lane & 15, l4 = lane >> 4;
  int wr = w >> 1, wc = w & 1;
  int srow8 = lane >> 3;
  int sslot = ((lane&7) ^ srow8) * 8;
  int n0 = bx*64;
  int tokc[4];
  #pragma unroll
  for (int c=0;c<4;++c){
    int rr = w*32 + c*8 + srow8;
    tokc[c] = atok[min(base + rr, TA-1)] & (S_LEN-1);
  }

  f32x4 acc1[4][2] = {}, acc2[4][2] = {};

  for (int k0 = 0; k0 < K; k0 += 64){
    __syncthreads();
    #pragma unroll
    for (int c=0;c<4;++c)
      gload16(A + (size_t)tokc[c]*K + k0 + sslot, &As[(w*32+c*8)*64]);
    #pragma unroll
    for (int c=0;c<2;++c){
      int rowb = w*16 + c*8 + srow8;
      size_t gb = (size_t)(n0+rowb)*K + k0 + sslot;
      gload16(B1p + gb, &B1s[(w*16+c*8)*64]);
      gload16(B2p + gb, &B2s[(w*16+c*8)*64]);
    }
    __syncthreads();
    #pragma unroll
    for (int kk=0; kk<2; ++kk){
      int xslot = ((kk*4 + l4) ^ (l15 & 7)) * 8;
      f16x8 af[4];
      #pragma unroll
      for (int mi=0; mi<4; ++mi)
        af[mi] = *(const f16x8*)&As[(wr*64 + mi*16 + l15)*64 + xslot];
      #pragma unroll
      for (int ni=0; ni<2; ++ni){
        int row = wc*32 + ni*16 + l15;
        f16x8 b1 = *(const f16x8*)&B1s[row*64 + xslot];
        f16x8 b2 = *(const f16x8*)&B2s[row*64 + xslot];
        #pragma unroll
        for (int mi=0; mi<4; ++mi){
          acc1[mi][ni] = __builtin_amdgcn_mfma_f32_16x16x32_f16(af[mi], b1, acc1[mi][ni], 0,0,0);
          acc2[mi][ni] = __builtin_amdgcn_mfma_f32_16x16x32_f16(af[mi], b2, acc2[mi][ni], 0,0,0);
        }
      }
    }
  }

  #pragma unroll
  for (int mi=0; mi<4; ++mi){
    #pragma unroll
    for (int ni=0; ni<2; ++ni){
      #pragma unroll
      for (int r=0; r<4; ++r){
        int rl = wr*64 + mi*16 + l4*4 + r;
        if (rl >= valid) continue;
        int col = n0 + wc*32 + ni*16 + l15;
        float a = acc1[mi][ni][r];
        float sl = a / (1.f + __expf(-a));
        Y[(size_t)(base + rl)*NF + col] = f2h(sl * acc2[mi][ni][r]);
      }
    }
  }
}

// ---------------- grouped GEMM for MoE, 128x64 tile, BK=64 ----------------
template<int MODE>
__global__ void __launch_bounds__(256) gemm_moe_k(
    const u16* __restrict__ A, const u16* __restrict__ BT, void* __restrict__ C,
    const u16* __restrict__ i1g, const float* __restrict__ aw,
    const int* __restrict__ atok, const int* __restrict__ counts,
    const int* __restrict__ offs, const int* __restrict__ ntl,
    const int* __restrict__ te, const int* __restrict__ trs)
{
  constexpr int K = 2048;
  __shared__ u16 As[128*64], Bs[64*64];
  int bx = blockIdx.x, by = blockIdx.y;
  xcd_swz(bx, by);
  if (by >= ntl[0]) return;
  int e = te[by];
  int rsu = trs[by];
  int base = offs[e] + rsu;
  int valid = min(128, counts[e] - rsu);
  const u16* Bp = BT + (size_t)e * 2048 * 2048;
  int tid = threadIdx.x, w = tid>>6, lane = tid&63;
  int l15 = lane & 15, l4 = lane >> 4;
  int wr = w >> 1, wc = w & 1;
  int srow8 = lane >> 3;
  int sslot = ((lane&7) ^ srow8) * 8;
  int n0 = bx*64;
  int tokc[4];
  #pragma unroll
  for (int c=0;c<4;++c){
    int rr = w*32 + c*8 + srow8;
    if constexpr (MODE == 2 || MODE == 3)
      tokc[c] = atok[min(base + rr, TA-1)] & (S_LEN-1);
    else
      tokc[c] = min(base + rr, TA-1);
  }

  f32x4 acc[4][2] = {};

  for (int k0 = 0; k0 < K; k0 += 64){
    __syncthreads();
    #pragma unroll
    for (int c=0;c<4;++c)
      gload16(A + (size_t)tokc[c]*K + k0 + sslot, &As[(w*32+c*8)*64]);
    #pragma unroll
    for (int c=0;c<2;++c){
      int rowb = w*16 + c*8 + srow8;
      gload16(Bp + (size_t)(n0+rowb)*K + k0 + sslot, &Bs[(w*16+c*8)*64]);
    }
    __syncthreads();
    #pragma unroll
    for (int kk=0; kk<2; ++kk){
      int xslot = ((kk*4 + l4) ^ (l15 & 7)) * 8;
      f16x8 af[4];
      #pragma unroll
      for (int mi=0; mi<4; ++mi)
        af[mi] = *(const f16x8*)&As[(wr*64 + mi*16 + l15)*64 + xslot];
      #pragma unroll
      for (int ni=0; ni<2; ++ni){
        f16x8 bfv = *(const f16x8*)&Bs[(wc*32 + ni*16 + l15)*64 + xslot];
        #pragma unroll
        for (int mi=0; mi<4; ++mi)
          acc[mi][ni] = __builtin_amdgcn_mfma_f32_16x16x32_f16(af[mi], bfv, acc[mi][ni], 0,0,0);
      }
    }
  }

  #pragma unroll
  for (int mi=0; mi<4; ++mi){
    #pragma unroll
    for (int ni=0; ni<2; ++ni){
      f32x4 v = acc[mi][ni];
      #pragma unroll
      for (int r=0; r<4; ++r){
        int rl = wr*64 + mi*16 + l4*4 + r;
        if (rl >= valid) continue;
        int col = n0 + wc*32 + ni*16 + l15;
        if constexpr (MODE == 2){
          ((u16*)C)[(size_t)(base + rl)*NF + col] = f2h(v[r]);
        } else if constexpr (MODE == 3){
          size_t idx = (size_t)(base + rl)*NF + col;
          float a = h2f(i1g[idx]);
          float sl = a / (1.f + __expf(-a));
          ((u16*)C)[idx] = f2h(sl * v[r]);
        } else {
          float wgt = aw[base + rl];
          ((u16*)C)[(size_t)(base + rl)*DMODEL + col] = f2h(v[r] * wgt);
        }
      }
    }
  }
}

__global__ void __launch_bounds__(256) combine_k(const float* __restrict__ H2,
    const u16* __restrict__ MOE, const int* __restrict__ slots, float* __restrict__ out){
  int t = blockIdx.x, tid = threadIdx.x;
  int s0 = slots[2*t], s1 = slots[2*t+1];
  const float* h2p = H2 + (size_t)t*DMODEL + tid*8;
  int4 b0 = *(const int4*)(MOE + (size_t)s0*DMODEL + tid*8);
  int4 b1 = *(const int4*)(MOE + (size_t)s1*DMODEL + tid*8);
  const u16* bp0 = (const u16*)&b0;
  const u16* bp1 = (const u16*)&b1;
  float* op = out + (size_t)t*DMODEL + tid*8;
  #pragma unroll
  for (int j=0;j<8;++j)
    op[j] = h2p[j] + h2f(bp0[j]) + h2f(bp1[j]);
}

// ---------------- launch ----------------
extern "C" void kernel_launch(void* const* d_in, const int* in_sizes, int n_in,
                              void* d_out, int out_size, void* d_ws, size_t ws_size,
                              hipStream_t stream){
  const float* hidden = (const float*)d_in[0];
  const int*   pos    = (const int*)d_in[1];
  const float* ln1w   = (const float*)d_in[2];
  const float* ln1b   = (const float*)d_in[3];
  const float* ln2w   = (const float*)d_in[4];
  const float* ln2b   = (const float*)d_in[5];
  const float* Wqkv   = (const float*)d_in[6];
  const float* Wout   = (const float*)d_in[7];
  const float* Wr     = (const float*)d_in[8];
  const float* w1     = (const float*)d_in[9];
  const float* v1     = (const float*)d_in[10];
  const float* w2     = (const float*)d_in[11];
  float* out = (float*)d_out;
  char* ws = (char*)d_ws;

  u16* woutTh = (u16*)(ws + WS_WOUTH);
  u16* woutTl = (u16*)(ws + WS_WOUTL);
  u16* qkvTh  = (u16*)(ws + WS_QKVTH);
  u16* qkvTl  = (u16*)(ws + WS_QKVTL);
  u16* h1h = (u16*)(ws + WS_H1H);
  u16* h1l = (u16*)(ws + WS_H1L);
  float* qkv = (float*)(ws + WS_QKV);
  u16* Qh = (u16*)(ws + WS_QH);
  u16* Ql = (u16*)(ws + WS_QL);
  u16* Kh = (u16*)(ws + WS_KH);
  u16* Kl = (u16*)(ws + WS_KL);
  u16* Vth = (u16*)(ws + WS_VTH);
  u16* Vtl = (u16*)(ws + WS_VTL);
  u16* Oh = (u16*)(ws + WS_OH);
  u16* Ol = (u16*)(ws + WS_OL);
  float* h2 = (float*)(ws + WS_H2);
  u16* x2 = (u16*)(ws + WS_X2);
  u16* i1 = (u16*)(ws + WS_I1);
  u16* Yb = (u16*)(ws + WS_Y);
  u16* moe = (u16*)(ws + WS_MOE);
  u16* wT0 = (u16*)(ws + WS_WT0);
  u16* wT1 = (u16*)(ws + WS_WT1);
  float* Opart = (float*)(ws + WS_QKV);
  float* Mlp   = (float*)(ws + WS_X2);
  char* sm = ws + WS_SM;
  float* invt = (float*)(sm + SM_INVT);
  int* counts = (int*)(sm + SM_COUNTS);
  int* fill   = (int*)(sm + SM_FILL);
  int* offs   = (int*)(sm + SM_OFFS);
  int* ntl    = (int*)(sm + SM_NT);
  int* te     = (int*)(sm + SM_TE);
  int* trs    = (int*)(sm + SM_TRS);
  int* e01    = (int*)(sm + SM_E01);
  float* w01  = (float*)(sm + SM_W01);
  int* atok   = (int*)(sm + SM_ATOK);
  float* aw   = (float*)(sm + SM_AW);
  int* slots  = (int*)(sm + SM_SLOT);

  init_k<<<1, 64, 0, stream>>>(counts, fill, invt);
  wsplit2_k<<<dim3(96,64,2), 256, 0, stream>>>(Wqkv, qkvTh, qkvTl, Wout, woutTh, woutTl);
  ln1_k<<<S_LEN, 256, 0, stream>>>(hidden, ln1w, ln1b, h1h, h1l);
  gemm32_k<0><<<dim3(48,16), 256, 0, stream>>>(h1h, h1l, qkvTh, qkvTl, qkv, nullptr);
  ropevt_k<<<S_LEN + 1024, 256, 0, stream>>>(qkv, pos, invt, Qh, Ql, Kh, Kl, Vth, Vtl);
  attn_k<<<768, 256, 0, stream>>>(Qh, Ql, Kh, Kl, Vth, Vtl, Oh, Ol, Opart, Mlp);
  merge_k<<<dim3(16,16), 256, 0, stream>>>(Opart, Mlp, Oh, Ol);
  gemm32_k<1><<<dim3(32,16), 256, 0, stream>>>(Oh, Ol, woutTh, woutTl, h2, hidden);
  ln2_router_k<<<S_LEN, 256, 0, stream>>>(h2, ln2w, ln2b, Wr, x2, e01, w01, counts);
  htiles_k<<<1, 64, 0, stream>>>(counts, offs, ntl, te, trs);
  scatter_k<<<8, 256, 0, stream>>>(e01, w01, offs, fill, atok, aw, slots);
  if (ws_size >= WS_BIG){
    wconvT2_k<<<dim3(32,32,16), 256, 0, stream>>>(w1, wT0, v1, wT1);
    gemm_moe13_k<<<dim3(32,40), 256, 0, stream>>>(x2, wT0, wT1, Yb,
        atok, counts, offs, ntl, te, trs);
    wconvT_k<<<dim3(32,32,8), 256, 0, stream>>>(w2, wT0);
    gemm_moe_k<4><<<dim3(32,40), 256, 0, stream>>>(Yb, wT0, moe, nullptr, aw,
        atok, counts, offs, ntl, te, trs);
  } else {
    wconvT_k<<<dim3(32,32,8), 256, 0, stream>>>(w1, wT0);
    gemm_moe_k<2><<<dim3(32,40), 256, 0, stream>>>(x2, wT0, i1, nullptr, nullptr,
        atok, counts, offs, ntl, te, trs);
    wconvT_k<<<dim3(32,32,8), 256, 0, stream>>>(v1, wT0);
    gemm_moe_k<3><<<dim3(32,40), 256, 0, stream>>>(x2, wT0, Yb, i1, nullptr,
        atok, counts, offs, ntl, te, trs);
    wconvT_k<<<dim3(32,32,8), 256, 0, stream>>>(w2, wT0);
    gemm_moe_k<4><<<dim3(32,40), 256, 0, stream>>>(Yb, wT0, moe, nullptr, aw,
        atok, counts, offs, ntl, te, trs);
  }
  combine_k<<<S_LEN, 256, 0, stream>>>(h2, moe, slots, out);
}